// Round 11
// baseline (688.000 us; speedup 1.0000x reference)
//
#include <hip/hip_runtime.h>

typedef unsigned char u8;
typedef unsigned short u16;
typedef _Float16 f16;
typedef __attribute__((ext_vector_type(4))) _Float16 f16x4;
typedef __attribute__((ext_vector_type(8))) _Float16 f16x8;
typedef __attribute__((ext_vector_type(4))) float f32x4;

#define D 128
#define PG 4  // csr padding granule

// ---- fused preprocessing, proportionally interleaved block roles ----
__global__ __launch_bounds__(256) void k_pre(
    const float* __restrict__ h_user, const float* __restrict__ h_item,
    const float* __restrict__ W,
    const int* __restrict__ fd, const int* __restrict__ cd,
    const int* __restrict__ cbd,
    u16* __restrict__ h_all, u16* __restrict__ Wtg,
    int* __restrict__ cnt, u8* __restrict__ pos,
    int NU, int NI, int nf, int nc, int ncb,
    int nbCnt, int nbCvtU, int nbCvtI) {
  int b = blockIdx.x;
  int T = gridDim.x;
  long before = (long)b * nbCnt / T;
  long after = (long)(b + 1) * nbCnt / T;
  if (after > before) {
    int e = (int)before * 256 + threadIdx.x;
    int d;
    if (e < nf)
      d = fd[e];
    else if (e < nf + nc)
      d = NU + cd[e - nf];
    else if (e < nf + nc + ncb)
      d = NU + NI + cbd[e - nf - nc];
    else
      return;
    int p = atomicAdd(&cnt[d], 1);
    pos[e] = (u8)p;
  } else {
    int v = b - (int)before;  // convert block id
    if (v < nbCvtU + nbCvtI) {
      bool isU = v < nbCvtU;
      int i = (isU ? v : v - nbCvtU) * 256 + threadIdx.x;
      int n8 = (isU ? NU : NI) * 16;
      if (i >= n8) return;
      const float4* ip = (const float4*)(isU ? h_user : h_item);
      u16* op = h_all + (isU ? 0 : (size_t)NU * D);
      float4 a = ip[i * 2], c = ip[i * 2 + 1];
      f16x8 vv = {(f16)a.x, (f16)a.y, (f16)a.z, (f16)a.w,
                  (f16)c.x, (f16)c.y, (f16)c.z, (f16)c.w};
      *(f16x8*)(op + (size_t)i * 8) = vv;
    } else {
      int idx = (v - nbCvtU - nbCvtI) * 256 + threadIdx.x;
      if (idx >= 9 * 16384) return;
      int mat = idx >> 14;
      int k = (idx >> 7) & 127;
      int n = idx & 127;
      ((f16*)Wtg)[(size_t)mat * 16384 + n * 128 + k] = (f16)W[idx];
    }
  }
}

__device__ __forceinline__ int pad4(int x) { return (x + (PG - 1)) & ~(PG - 1); }

// ---------------- device-wide exclusive scan over PADDED counts ----------
__global__ __launch_bounds__(256) void k_scanA(const int* __restrict__ cnt,
                                               int* __restrict__ part, int n) {
  int t = threadIdx.x;
  int idx = blockIdx.x * 1024 + t * 4;
  int s = 0;
  if (idx + 3 < n) {
    int4 c = *(const int4*)(cnt + idx);
    s = pad4(c.x) + pad4(c.y) + pad4(c.z) + pad4(c.w);
  } else {
#pragma unroll
    for (int j = 0; j < 4; ++j)
      if (idx + j < n) s += pad4(cnt[idx + j]);
  }
  for (int off = 1; off < 64; off <<= 1) s += __shfl_down(s, off, 64);
  __shared__ int ws[4];
  if ((t & 63) == 0) ws[t >> 6] = s;
  __syncthreads();
  if (t == 0) part[blockIdx.x] = ws[0] + ws[1] + ws[2] + ws[3];
}

__global__ __launch_bounds__(1024) void k_scanB(int* __restrict__ part, int n_part) {
  __shared__ int sh[1024];
  int t = threadIdx.x;
  int v = (t < n_part) ? part[t] : 0;
  sh[t] = v;
  __syncthreads();
  for (int off = 1; off < 1024; off <<= 1) {
    int u = (t >= off) ? sh[t - off] : 0;
    __syncthreads();
    sh[t] += u;
    __syncthreads();
  }
  if (t < n_part) part[t] = sh[t] - v;  // exclusive
}

__global__ __launch_bounds__(256) void k_scanC(const int* __restrict__ cnt,
                                               const int* __restrict__ part,
                                               int* __restrict__ rs, int n) {
  int t = threadIdx.x;
  int idx = blockIdx.x * 1024 + t * 4;
  int v0 = 0, v1 = 0, v2 = 0, v3 = 0;
  if (idx + 3 < n) {
    int4 c = *(const int4*)(cnt + idx);
    v0 = pad4(c.x);
    v1 = pad4(c.y);
    v2 = pad4(c.z);
    v3 = pad4(c.w);
  } else {
    if (idx < n) v0 = pad4(cnt[idx]);
    if (idx + 1 < n) v1 = pad4(cnt[idx + 1]);
    if (idx + 2 < n) v2 = pad4(cnt[idx + 2]);
    if (idx + 3 < n) v3 = pad4(cnt[idx + 3]);
  }
  int s = v0 + v1 + v2 + v3;
  int inc = s;
  int lane = t & 63, w = t >> 6;
  for (int off = 1; off < 64; off <<= 1) {
    int u = __shfl_up(inc, off, 64);
    if (lane >= off) inc += u;
  }
  __shared__ int ws[4];
  if (lane == 63) ws[w] = inc;
  __syncthreads();
  int woff = 0;
  for (int i = 0; i < w; ++i) woff += ws[i];
  int ex = part[blockIdx.x] + woff + inc - s;
  int4 r;
  r.x = ex;
  r.y = ex + v0;
  r.z = r.y + v1;
  r.w = r.z + v2;
  if (idx + 3 < n)
    *(int4*)(rs + idx) = r;
  else {
    if (idx < n) rs[idx] = r.x;
    if (idx + 1 < n) rs[idx + 1] = r.y;
    if (idx + 2 < n) rs[idx + 2] = r.z;
    if (idx + 3 < n) rs[idx + 3] = r.w;
  }
  if (idx <= n - 1 && n - 1 < idx + 4) {
    int j = n - 1 - idx;
    int incl = (j == 0) ? r.x + v0 : (j == 1) ? r.y + v1 : (j == 2) ? r.z + v2 : r.w + v3;
    rs[n] = incl;
  }
}

// ---- fill dummy (pad) slots with the zero-row index ----
__global__ __launch_bounds__(256) void k_padfill(const int* __restrict__ rs,
                                                 const int* __restrict__ cnt,
                                                 int* __restrict__ csr, int N3, int ZR) {
  int d = blockIdx.x * 256 + threadIdx.x;
  if (d >= N3) return;
  int deg = cnt[d];
  int degp = pad4(deg);
  int base = rs[d] + deg;
#pragma unroll
  for (int j = 0; j < PG - 1; ++j)
    if (j < degp - deg) csr[base + j] = ZR;
}

// ------- CSR build pass 2: atomic-free scatter using recorded slots ---------
__global__ __launch_bounds__(256) void k_fillpos(
    const int* __restrict__ fs, const int* __restrict__ fd,
    const int* __restrict__ cs, const int* __restrict__ cd,
    const int* __restrict__ cbs, const int* __restrict__ cbd,
    const int* __restrict__ rs, const u8* __restrict__ pos,
    int* __restrict__ csr, int NU, int NI, int nf, int nc, int ncb) {
  int e = blockIdx.x * 256 + threadIdx.x;
  int d, s;
  if (e < nf) {
    d = fd[e];
    s = fs[e];
  } else if (e < nf + nc) {
    d = NU + cd[e - nf];
    s = cs[e - nf];
  } else if (e < nf + nc + ncb) {
    d = NU + NI + cbd[e - nf - nc];
    s = cbs[e - nf - nc] + NU;
  } else
    return;
  csr[rs[d] + (int)pos[e]] = s;
}

// ---- gather node means directly into MFMA A-fragment layout ----
// lane: r=lane&15 (node), g=lane>>4 (k-slice). a[ks] holds node r's mean
// at k = ks*32 + g*8. Branch-free via ZR (zero-row) substitution.
__device__ __forceinline__ int gather_frag(
    f16x8 a[4], const char* __restrict__ hb, const int* __restrict__ csr,
    const int* __restrict__ rs, const int* __restrict__ cnt, int gnode, int ZR) {
  int lane = threadIdx.x & 63;
  int g = lane >> 4;
  int e = rs[gnode], en = rs[gnode + 1];
  int deg = cnt[gnode];
  unsigned off = (unsigned)g * 16u;
  f16x8 a0 = {0, 0, 0, 0, 0, 0, 0, 0}, a1 = a0, a2 = a0, a3 = a0;
  while (__any(e < en)) {
    bool p = e < en;
    int s0 = p ? csr[e] : ZR;      // granule-4 padding: p covers e and e+1
    int s1 = p ? csr[e + 1] : ZR;
    unsigned b0 = (unsigned)s0 * 256u + off;
    unsigned b1 = (unsigned)s1 * 256u + off;
    f16x8 v00 = *(const f16x8*)(hb + b0);
    f16x8 v01 = *(const f16x8*)(hb + b0 + 64u);
    f16x8 v02 = *(const f16x8*)(hb + b0 + 128u);
    f16x8 v03 = *(const f16x8*)(hb + b0 + 192u);
    f16x8 v10 = *(const f16x8*)(hb + b1);
    f16x8 v11 = *(const f16x8*)(hb + b1 + 64u);
    f16x8 v12 = *(const f16x8*)(hb + b1 + 128u);
    f16x8 v13 = *(const f16x8*)(hb + b1 + 192u);
    a0 += v00;
    a1 += v01;
    a2 += v02;
    a3 += v03;
    a0 += v10;
    a1 += v11;
    a2 += v12;
    a3 += v13;
    e += 2;
  }
  float invf = deg > 0 ? 1.0f / (float)deg : 0.f;
  f16 hinv = (f16)invf;
  a[0] = a0 * hinv;
  a[1] = a1 * hinv;
  a[2] = a2 * hinv;
  a[3] = a3 * hinv;
  return deg;
}

// ---- acc += Mean(16 nodes) @ W; W streamed from global/L2 ----
__device__ __forceinline__ void mfma_frag(f32x4 acc[8], const f16x8 a[4],
                                          const u16* __restrict__ Wmat) {
  int lane = threadIdx.x & 63;
  int r = lane & 15, g = lane >> 4;
  const f16* Wg = (const f16*)Wmat;
#pragma unroll
  for (int half = 0; half < 2; ++half) {
#pragma unroll
    for (int ks = 0; ks < 4; ++ks) {
      f16x8 bf[4];
#pragma unroll
      for (int n4 = 0; n4 < 4; ++n4) {
        int n = half * 4 + n4;
        bf[n4] = *(const f16x8*)(Wg + (n * 16 + r) * D + ks * 32 + g * 8);
      }
#pragma unroll
      for (int n4 = 0; n4 < 4; ++n4)
        acc[half * 4 + n4] =
            __builtin_amdgcn_mfma_f32_16x16x32_f16(bf[n4], a[ks], acc[half * 4 + n4], 0, 0, 0);
    }
  }
}

// ---- fused per-layer kernel: wave = 16 output rows, no LDS, no barriers ----
template <int OUTF32>
__global__ __launch_bounds__(256) void k_layer(
    const u16* __restrict__ hcur, const int* __restrict__ csr,
    const int* __restrict__ rs_all, const int* __restrict__ cnt,
    const u16* __restrict__ Wl, const float* __restrict__ bl,
    u16* __restrict__ hnxt, float* __restrict__ out,
    int NU, int NI, int nwI, int nwU, int ZR) {
  int wid = blockIdx.x * 4 + (threadIdx.x >> 6);
  if (wid >= nwI + nwU) return;
  int lane = threadIdx.x & 63;
  int r = lane & 15, g = lane >> 4;
  const char* hb = (const char*)hcur;

  bool isItem = wid < nwI;
  int node = (isItem ? wid : wid - nwI) * 16 + r;
  int Ntgt = isItem ? NI : NU;
  bool valid = node < Ntgt;
  int nodec = valid ? node : Ntgt - 1;

  f32x4 acc[8];
#pragma unroll
  for (int n = 0; n < 8; ++n) acc[n] = (f32x4){0.f, 0.f, 0.f, 0.f};

  f16x8 a[4];
  int gA = isItem ? NU + nodec : nodec;
  int degA = gather_frag(a, hb, csr, rs_all, cnt, gA, ZR);
  mfma_frag(acc, a, isItem ? Wl + 16384 : Wl);
  int degB = 0;
  if (!isItem) {
    degB = gather_frag(a, hb, csr, rs_all, cnt, NU + NI + nodec, ZR);
    mfma_frag(acc, a, Wl + 2 * 16384);
  }

  // epilogue: lane stores node (lane&15), cols n*16 + g*4 .. +3
  const float* bA = isItem ? bl + D : bl;
  long orow = (long)(isItem ? NU + node : node) * D;
  bool mA = degA > 0, mB = degB > 0;
  if (valid) {
#pragma unroll
    for (int n = 0; n < 8; ++n) {
      int col = n * 16 + g * 4;
      float4 ba = *(const float4*)&bA[col];
      float4 vv;
      vv.x = acc[n][0];
      vv.y = acc[n][1];
      vv.z = acc[n][2];
      vv.w = acc[n][3];
      if (mA) {
        vv.x += ba.x;
        vv.y += ba.y;
        vv.z += ba.z;
        vv.w += ba.w;
      }
      if (mB) {
        float4 bb2 = *(const float4*)&bl[2 * D + col];
        vv.x += bb2.x;
        vv.y += bb2.y;
        vv.z += bb2.z;
        vv.w += bb2.w;
      }
      vv.x = vv.x > 0.f ? vv.x : 0.01f * vv.x;
      vv.y = vv.y > 0.f ? vv.y : 0.01f * vv.y;
      vv.z = vv.z > 0.f ? vv.z : 0.01f * vv.z;
      vv.w = vv.w > 0.f ? vv.w : 0.01f * vv.w;
      if (OUTF32) {
        *(float4*)&out[orow + col] = vv;
      } else {
        f16x4 h = {(f16)vv.x, (f16)vv.y, (f16)vv.z, (f16)vv.w};
        *(f16x4*)((f16*)hnxt + orow + col) = h;
      }
    }
  }
}

extern "C" void kernel_launch(void* const* d_in, const int* in_sizes, int n_in,
                              void* d_out, int out_size, void* d_ws, size_t ws_size,
                              hipStream_t stream) {
  const float* h_user = (const float*)d_in[0];
  const float* h_item = (const float*)d_in[1];
  const float* W = (const float*)d_in[2];
  const float* bb = (const float*)d_in[3];
  const int* f_src = (const int*)d_in[4];
  const int* f_dst = (const int*)d_in[5];
  const int* c_src = (const int*)d_in[6];
  const int* c_dst = (const int*)d_in[7];
  const int* cb_src = (const int*)d_in[8];
  const int* cb_dst = (const int*)d_in[9];

  const int NU = in_sizes[0] / D;
  const int NI = in_sizes[1] / D;
  const int nEf = in_sizes[4], nEc = in_sizes[6], nEcb = in_sizes[8];
  const int N3 = NU + NI + NU;
  const int nE = nEf + nEc + nEcb;
  const int ZR = NU + NI;  // zero-row index in h buffers

  char* p = (char*)d_ws;
  auto alloc = [&](size_t bytes) {
    char* r = p;
    p += (bytes + 255) & ~(size_t)255;
    return r;
  };
  int* cnt = (int*)alloc((size_t)N3 * 4);
  int* rs_all = (int*)alloc((size_t)(N3 + 1) * 4);
  int* part = (int*)alloc(1024 * 4);
  u16* Wtg = (u16*)alloc((size_t)9 * 16384 * 2);
  int* csr_all = (int*)alloc(((size_t)nE + (size_t)(PG - 1) * N3) * 4);  // padded
  u16* hA = (u16*)alloc((size_t)(NU + NI + 1) * D * 2);  // [hu|hi|zero] ping
  u16* hB = (u16*)alloc((size_t)(NU + NI + 1) * D * 2);  // pong
  u8* pos = (u8*)hB;  // aliased: dead before layer0 writes hB
  (void)ws_size;      // ~117 MB total

  hipMemsetAsync(cnt, 0, (size_t)N3 * 4, stream);
  hipMemsetAsync(hA + (size_t)ZR * D, 0, D * 2, stream);
  hipMemsetAsync(hB + (size_t)ZR * D, 0, D * 2, stream);

  int nbCnt = (nE + 255) / 256;
  int nbCvtU = (NU * 16 + 255) / 256;
  int nbCvtI = (NI * 16 + 255) / 256;
  int nbW = (9 * 16384 + 255) / 256;
  k_pre<<<nbCnt + nbCvtU + nbCvtI + nbW, 256, 0, stream>>>(
      h_user, h_item, W, f_dst, c_dst, cb_dst, hA, Wtg, cnt, pos,
      NU, NI, nEf, nEc, nEcb, nbCnt, nbCvtU, nbCvtI);

  int n_part = (N3 + 1023) / 1024;
  k_scanA<<<n_part, 256, 0, stream>>>(cnt, part, N3);
  k_scanB<<<1, 1024, 0, stream>>>(part, n_part);
  k_scanC<<<n_part, 256, 0, stream>>>(cnt, part, rs_all, N3);

  k_padfill<<<(N3 + 255) / 256, 256, 0, stream>>>(rs_all, cnt, csr_all, N3, ZR);
  k_fillpos<<<(nE + 255) / 256, 256, 0, stream>>>(f_src, f_dst, c_src, c_dst,
                                                  cb_src, cb_dst, rs_all, pos,
                                                  csr_all, NU, NI, nEf, nEc, nEcb);

  int nwI = (NI + 15) / 16;
  int nwU = (NU + 15) / 16;
  int nblk = (nwI + nwU + 3) / 4;

  u16* hcur = hA;
  u16* hnxt = hB;
  for (int l = 0; l < 3; ++l) {
    const u16* Wl = Wtg + (size_t)l * 3 * 16384;
    const float* bl = bb + (size_t)l * 3 * D;
    if (l < 2)
      k_layer<0><<<nblk, 256, 0, stream>>>(hcur, csr_all, rs_all, cnt, Wl, bl,
                                           hnxt, (float*)d_out, NU, NI, nwI, nwU, ZR);
    else
      k_layer<1><<<nblk, 256, 0, stream>>>(hcur, csr_all, rs_all, cnt, Wl, bl,
                                           hnxt, (float*)d_out, NU, NI, nwI, nwU, ZR);
    u16* t = hcur;
    hcur = hnxt;
    hnxt = t;
  }
}

// Round 12
// 541.534 us; speedup vs baseline: 1.2705x; 1.2705x over previous
//
#include <hip/hip_runtime.h>

typedef unsigned char u8;
typedef unsigned short u16;
typedef _Float16 f16;
typedef __attribute__((ext_vector_type(4))) _Float16 f16x4;
typedef __attribute__((ext_vector_type(8))) _Float16 f16x8;
typedef __attribute__((ext_vector_type(4))) float f32x4;

#define D 128
#define PG 4  // csr padding granule

// ---- fused preprocessing, proportionally interleaved block roles ----
__global__ __launch_bounds__(256) void k_pre(
    const float* __restrict__ h_user, const float* __restrict__ h_item,
    const float* __restrict__ W,
    const int* __restrict__ fd, const int* __restrict__ cd,
    const int* __restrict__ cbd,
    u16* __restrict__ h_all, u16* __restrict__ Wtg,
    int* __restrict__ cnt, u8* __restrict__ pos,
    int NU, int NI, int nf, int nc, int ncb,
    int nbCnt, int nbCvtU, int nbCvtI) {
  int b = blockIdx.x;
  int T = gridDim.x;
  long before = (long)b * nbCnt / T;
  long after = (long)(b + 1) * nbCnt / T;
  if (after > before) {
    int e = (int)before * 256 + threadIdx.x;
    int d;
    if (e < nf)
      d = fd[e];
    else if (e < nf + nc)
      d = NU + cd[e - nf];
    else if (e < nf + nc + ncb)
      d = NU + NI + cbd[e - nf - nc];
    else
      return;
    int p = atomicAdd(&cnt[d], 1);
    pos[e] = (u8)p;
  } else {
    int v = b - (int)before;  // convert block id
    if (v < nbCvtU + nbCvtI) {
      bool isU = v < nbCvtU;
      int i = (isU ? v : v - nbCvtU) * 256 + threadIdx.x;
      int n8 = (isU ? NU : NI) * 16;
      if (i >= n8) return;
      const float4* ip = (const float4*)(isU ? h_user : h_item);
      u16* op = h_all + (isU ? 0 : (size_t)NU * D);
      float4 a = ip[i * 2], c = ip[i * 2 + 1];
      f16x8 vv = {(f16)a.x, (f16)a.y, (f16)a.z, (f16)a.w,
                  (f16)c.x, (f16)c.y, (f16)c.z, (f16)c.w};
      *(f16x8*)(op + (size_t)i * 8) = vv;
    } else {
      int idx = (v - nbCvtU - nbCvtI) * 256 + threadIdx.x;
      if (idx >= 9 * 16384) return;
      int mat = idx >> 14;
      int k = (idx >> 7) & 127;
      int n = idx & 127;
      ((f16*)Wtg)[(size_t)mat * 16384 + n * 128 + k] = (f16)W[idx];
    }
  }
}

__device__ __forceinline__ int pad4(int x) { return (x + (PG - 1)) & ~(PG - 1); }

// ---------------- device-wide exclusive scan over PADDED counts ----------
__global__ __launch_bounds__(256) void k_scanA(const int* __restrict__ cnt,
                                               int* __restrict__ part, int n) {
  int t = threadIdx.x;
  int idx = blockIdx.x * 1024 + t * 4;
  int s = 0;
  if (idx + 3 < n) {
    int4 c = *(const int4*)(cnt + idx);
    s = pad4(c.x) + pad4(c.y) + pad4(c.z) + pad4(c.w);
  } else {
#pragma unroll
    for (int j = 0; j < 4; ++j)
      if (idx + j < n) s += pad4(cnt[idx + j]);
  }
  for (int off = 1; off < 64; off <<= 1) s += __shfl_down(s, off, 64);
  __shared__ int ws[4];
  if ((t & 63) == 0) ws[t >> 6] = s;
  __syncthreads();
  if (t == 0) part[blockIdx.x] = ws[0] + ws[1] + ws[2] + ws[3];
}

__global__ __launch_bounds__(1024) void k_scanB(int* __restrict__ part, int n_part) {
  __shared__ int sh[1024];
  int t = threadIdx.x;
  int v = (t < n_part) ? part[t] : 0;
  sh[t] = v;
  __syncthreads();
  for (int off = 1; off < 1024; off <<= 1) {
    int u = (t >= off) ? sh[t - off] : 0;
    __syncthreads();
    sh[t] += u;
    __syncthreads();
  }
  if (t < n_part) part[t] = sh[t] - v;  // exclusive
}

__global__ __launch_bounds__(256) void k_scanC(const int* __restrict__ cnt,
                                               const int* __restrict__ part,
                                               int* __restrict__ rs, int n) {
  int t = threadIdx.x;
  int idx = blockIdx.x * 1024 + t * 4;
  int v0 = 0, v1 = 0, v2 = 0, v3 = 0;
  if (idx + 3 < n) {
    int4 c = *(const int4*)(cnt + idx);
    v0 = pad4(c.x);
    v1 = pad4(c.y);
    v2 = pad4(c.z);
    v3 = pad4(c.w);
  } else {
    if (idx < n) v0 = pad4(cnt[idx]);
    if (idx + 1 < n) v1 = pad4(cnt[idx + 1]);
    if (idx + 2 < n) v2 = pad4(cnt[idx + 2]);
    if (idx + 3 < n) v3 = pad4(cnt[idx + 3]);
  }
  int s = v0 + v1 + v2 + v3;
  int inc = s;
  int lane = t & 63, w = t >> 6;
  for (int off = 1; off < 64; off <<= 1) {
    int u = __shfl_up(inc, off, 64);
    if (lane >= off) inc += u;
  }
  __shared__ int ws[4];
  if (lane == 63) ws[w] = inc;
  __syncthreads();
  int woff = 0;
  for (int i = 0; i < w; ++i) woff += ws[i];
  int ex = part[blockIdx.x] + woff + inc - s;
  int4 r;
  r.x = ex;
  r.y = ex + v0;
  r.z = r.y + v1;
  r.w = r.z + v2;
  if (idx + 3 < n)
    *(int4*)(rs + idx) = r;
  else {
    if (idx < n) rs[idx] = r.x;
    if (idx + 1 < n) rs[idx + 1] = r.y;
    if (idx + 2 < n) rs[idx + 2] = r.z;
    if (idx + 3 < n) rs[idx + 3] = r.w;
  }
  if (idx <= n - 1 && n - 1 < idx + 4) {
    int j = n - 1 - idx;
    int incl = (j == 0) ? r.x + v0 : (j == 1) ? r.y + v1 : (j == 2) ? r.z + v2 : r.w + v3;
    rs[n] = incl;
  }
}

// ---- CSR fill: real slots (atomic-free via pos) + dummy pad slots, fused ----
__global__ __launch_bounds__(256) void k_fill2(
    const int* __restrict__ fs, const int* __restrict__ fd,
    const int* __restrict__ cs, const int* __restrict__ cd,
    const int* __restrict__ cbs, const int* __restrict__ cbd,
    const int* __restrict__ rs, const int* __restrict__ cnt,
    const u8* __restrict__ pos, int* __restrict__ csr,
    int NU, int NI, int nf, int nc, int ncb, int nbFill, int N3, int ZR) {
  if ((int)blockIdx.x < nbFill) {
    int e = blockIdx.x * 256 + threadIdx.x;
    int d, s;
    if (e < nf) {
      d = fd[e];
      s = fs[e];
    } else if (e < nf + nc) {
      d = NU + cd[e - nf];
      s = cs[e - nf];
    } else if (e < nf + nc + ncb) {
      d = NU + NI + cbd[e - nf - nc];
      s = cbs[e - nf - nc] + NU;
    } else
      return;
    csr[rs[d] + (int)pos[e]] = s;
  } else {
    int d = (blockIdx.x - nbFill) * 256 + threadIdx.x;
    if (d >= N3) return;
    int deg = cnt[d];
    int degp = pad4(deg);
    int base = rs[d] + deg;
#pragma unroll
    for (int j = 0; j < PG - 1; ++j)
      if (j < degp - deg) csr[base + j] = ZR;
  }
}

// ---- mean aggregation: 4 nodes/wave, 16 lanes/node, f16 accum ----
// padded CSR (4-aligned segments) -> int4 index loads, branch-free body.
__global__ __launch_bounds__(256) void k_agg3(
    const u16* __restrict__ h_all, const int* __restrict__ csr,
    const int* __restrict__ rs, const int* __restrict__ cnt,
    u16* __restrict__ M_all, int N3) {
  int wave = (blockIdx.x * 256 + threadIdx.x) >> 6;
  int lane = threadIdx.x & 63;
  int l16 = lane & 15;
  int w = wave * 4 + (lane >> 4);
  bool valid = w < N3;
  int wc = valid ? w : 0;
  int e = rs[wc];
  int en = valid ? rs[wc + 1] : e;
  int deg = valid ? cnt[wc] : 0;
  f16x8 acc0 = {0, 0, 0, 0, 0, 0, 0, 0};
  f16x8 acc1 = {0, 0, 0, 0, 0, 0, 0, 0};
  const char* hb = (const char*)h_all;
  const int4* csr4 = (const int4*)csr;
  unsigned loff = (unsigned)l16 * 16u;

  int en8 = e + ((en - e) & ~7);
  while (e < en8) {
    int4 c0 = csr4[e >> 2];
    int4 c1 = csr4[(e >> 2) + 1];
    f16x8 v0 = *(const f16x8*)(hb + ((unsigned)c0.x * 256u + loff));
    f16x8 v1 = *(const f16x8*)(hb + ((unsigned)c0.y * 256u + loff));
    f16x8 v2 = *(const f16x8*)(hb + ((unsigned)c0.z * 256u + loff));
    f16x8 v3 = *(const f16x8*)(hb + ((unsigned)c0.w * 256u + loff));
    f16x8 v4 = *(const f16x8*)(hb + ((unsigned)c1.x * 256u + loff));
    f16x8 v5 = *(const f16x8*)(hb + ((unsigned)c1.y * 256u + loff));
    f16x8 v6 = *(const f16x8*)(hb + ((unsigned)c1.z * 256u + loff));
    f16x8 v7 = *(const f16x8*)(hb + ((unsigned)c1.w * 256u + loff));
    acc0 += v0;
    acc1 += v1;
    acc0 += v2;
    acc1 += v3;
    acc0 += v4;
    acc1 += v5;
    acc0 += v6;
    acc1 += v7;
    e += 8;
  }
  if (e < en) {  // exactly 4 remain (padded)
    int4 c0 = csr4[e >> 2];
    f16x8 v0 = *(const f16x8*)(hb + ((unsigned)c0.x * 256u + loff));
    f16x8 v1 = *(const f16x8*)(hb + ((unsigned)c0.y * 256u + loff));
    f16x8 v2 = *(const f16x8*)(hb + ((unsigned)c0.z * 256u + loff));
    f16x8 v3 = *(const f16x8*)(hb + ((unsigned)c0.w * 256u + loff));
    acc0 += v0;
    acc1 += v1;
    acc0 += v2;
    acc1 += v3;
  }

  if (valid) {
    float invf = deg > 0 ? 1.0f / (float)deg : 0.f;
    f16 hinv = (f16)invf;
    f16x8 t = acc0 + acc1;
    f16x8 r = t * hinv;
    *(f16x8*)((char*)M_all + ((unsigned)wc * 256u + loff)) = r;
  }
}

// -------- GEMM body: no LDS, W streamed from global/L2, transposed MFMA ------
template <int NE, int OUTF32>
__device__ __forceinline__ void gemm_body(
    const u16* __restrict__ mA, const u16* __restrict__ mBp,
    const u16* __restrict__ wtA, const u16* __restrict__ wtB,  // fp16 [n][k]
    const float* __restrict__ bA, const float* __restrict__ bB,
    const int* __restrict__ cntA, const int* __restrict__ cntB,
    u16* __restrict__ o16, float* __restrict__ o32, int M, int blk) {
  int tid = threadIdx.x, lane = tid & 63, w = tid >> 6;
  int lr = lane & 15;
  int lk = (lane >> 4) * 8;
  long row0 = (long)blk * 128 + w * 32;

  f32x4 acc[2][8];
#pragma unroll
  for (int rt = 0; rt < 2; rt++)
#pragma unroll
    for (int n = 0; n < 8; n++) acc[rt][n] = (f32x4){0.f, 0.f, 0.f, 0.f};

#pragma unroll
  for (int e = 0; e < NE; ++e) {
    const f16* mm = (const f16*)((e == 0) ? mA : mBp);
    const f16* Wg = (const f16*)((e == 0) ? wtA : wtB);
#pragma unroll
    for (int ks = 0; ks < 4; ++ks) {
      int k0 = ks * 32 + lk;
      f16x8 bf[8];
#pragma unroll
      for (int n = 0; n < 8; n++) bf[n] = *(const f16x8*)(Wg + (n * 16 + lr) * D + k0);
#pragma unroll
      for (int rt = 0; rt < 2; rt++) {
        long r = row0 + rt * 16 + lr;
        if (r >= M) r = M - 1;  // clamped load; store guarded
        f16x8 af = *(const f16x8*)(mm + r * D + k0);
#pragma unroll
        for (int n = 0; n < 8; n++)
          acc[rt][n] = __builtin_amdgcn_mfma_f32_16x16x32_f16(bf[n], af, acc[rt][n], 0, 0, 0);
      }
    }
  }

  int g4 = (lane >> 4) * 4;
  float4 bAr[8], bBr[8];
#pragma unroll
  for (int n = 0; n < 8; n++) {
    bAr[n] = *(const float4*)&bA[n * 16 + g4];
    if (NE == 2) bBr[n] = *(const float4*)&bB[n * 16 + g4];
  }

#pragma unroll
  for (int rt = 0; rt < 2; rt++) {
    long r = row0 + rt * 16 + lr;
    if (r < M) {
      bool mAok = cntA[r] > 0;
      bool mBok = (NE == 2) && (cntB[r] > 0);
#pragma unroll
      for (int n = 0; n < 8; n++) {
        float4 vv;
        vv.x = acc[rt][n][0];
        vv.y = acc[rt][n][1];
        vv.z = acc[rt][n][2];
        vv.w = acc[rt][n][3];
        if (mAok) {
          vv.x += bAr[n].x;
          vv.y += bAr[n].y;
          vv.z += bAr[n].z;
          vv.w += bAr[n].w;
        }
        if (mBok) {
          vv.x += bBr[n].x;
          vv.y += bBr[n].y;
          vv.z += bBr[n].z;
          vv.w += bBr[n].w;
        }
        vv.x = vv.x > 0.f ? vv.x : 0.01f * vv.x;
        vv.y = vv.y > 0.f ? vv.y : 0.01f * vv.y;
        vv.z = vv.z > 0.f ? vv.z : 0.01f * vv.z;
        vv.w = vv.w > 0.f ? vv.w : 0.01f * vv.w;
        int col = n * 16 + g4;
        if (OUTF32) {
          *(float4*)&o32[r * D + col] = vv;
        } else {
          f16x4 h = {(f16)vv.x, (f16)vv.y, (f16)vv.z, (f16)vv.w};
          *(f16x4*)((f16*)o16 + r * D + col) = h;
        }
      }
    }
  }
}

// ---------------- fused per-layer GEMM: item blocks + user blocks ----------
template <int OUTF32>
__global__ __launch_bounds__(256) void k_gemm2(
    const u16* __restrict__ M_all, const u16* __restrict__ Wl,
    const float* __restrict__ bl, const int* __restrict__ cnt,
    u16* __restrict__ h_all, float* __restrict__ out,
    int NU, int NI, int nbI) {
  if ((int)blockIdx.x < nbI) {
    gemm_body<1, OUTF32>(M_all + (size_t)NU * D, nullptr,
                         Wl + 16384, nullptr,
                         bl + D, nullptr,
                         cnt + NU, nullptr,
                         h_all + (size_t)NU * D, out + (size_t)NU * D, NI,
                         blockIdx.x);
  } else {
    gemm_body<2, OUTF32>(M_all, M_all + (size_t)(NU + NI) * D,
                         Wl, Wl + 2 * 16384,
                         bl, bl + 2 * D,
                         cnt, cnt + NU + NI,
                         h_all, out, NU, blockIdx.x - nbI);
  }
}

extern "C" void kernel_launch(void* const* d_in, const int* in_sizes, int n_in,
                              void* d_out, int out_size, void* d_ws, size_t ws_size,
                              hipStream_t stream) {
  const float* h_user = (const float*)d_in[0];
  const float* h_item = (const float*)d_in[1];
  const float* W = (const float*)d_in[2];
  const float* bb = (const float*)d_in[3];
  const int* f_src = (const int*)d_in[4];
  const int* f_dst = (const int*)d_in[5];
  const int* c_src = (const int*)d_in[6];
  const int* c_dst = (const int*)d_in[7];
  const int* cb_src = (const int*)d_in[8];
  const int* cb_dst = (const int*)d_in[9];

  const int NU = in_sizes[0] / D;
  const int NI = in_sizes[1] / D;
  const int nEf = in_sizes[4], nEc = in_sizes[6], nEcb = in_sizes[8];
  const int N3 = NU + NI + NU;
  const int nE = nEf + nEc + nEcb;
  const int ZR = NU + NI;  // zero-row index in h_all

  char* p = (char*)d_ws;
  auto alloc = [&](size_t bytes) {
    char* r = p;
    p += (bytes + 255) & ~(size_t)255;
    return r;
  };
  int* cnt = (int*)alloc((size_t)N3 * 4);
  int* rs_all = (int*)alloc((size_t)(N3 + 1) * 4);
  int* part = (int*)alloc(1024 * 4);
  u16* Wtg = (u16*)alloc((size_t)9 * 16384 * 2);
  int* csr_all = (int*)alloc(((size_t)nE + (size_t)(PG - 1) * N3) * 4);  // padded
  u16* h_all = (u16*)alloc((size_t)(NU + NI + 1) * D * 2);  // [hu | hi | zero-row]
  u16* M_all = (u16*)alloc((size_t)N3 * D * 2);             // [Mf | Mc | Mcb]
  u8* pos = (u8*)M_all;  // aliased: dead before first agg write
  (void)ws_size;         // ~142.0 MB total (within proven bound)

  hipMemsetAsync(cnt, 0, (size_t)N3 * 4, stream);
  hipMemsetAsync(h_all + (size_t)ZR * D, 0, D * 2, stream);  // zero row

  int nbCnt = (nE + 255) / 256;
  int nbCvtU = (NU * 16 + 255) / 256;
  int nbCvtI = (NI * 16 + 255) / 256;
  int nbW = (9 * 16384 + 255) / 256;
  k_pre<<<nbCnt + nbCvtU + nbCvtI + nbW, 256, 0, stream>>>(
      h_user, h_item, W, f_dst, c_dst, cb_dst, h_all, Wtg, cnt, pos,
      NU, NI, nEf, nEc, nEcb, nbCnt, nbCvtU, nbCvtI);

  int n_part = (N3 + 1023) / 1024;
  k_scanA<<<n_part, 256, 0, stream>>>(cnt, part, N3);
  k_scanB<<<1, 1024, 0, stream>>>(part, n_part);
  k_scanC<<<n_part, 256, 0, stream>>>(cnt, part, rs_all, N3);

  int nbFill = (nE + 255) / 256;
  int nbPad = (N3 + 255) / 256;
  k_fill2<<<nbFill + nbPad, 256, 0, stream>>>(f_src, f_dst, c_src, c_dst,
                                              cb_src, cb_dst, rs_all, cnt, pos,
                                              csr_all, NU, NI, nEf, nEc, nEcb,
                                              nbFill, N3, ZR);

  int nbI = (NI + 127) / 128;
  int nbU = (NU + 127) / 128;
  int agg_blocks = ((N3 + 3) / 4 + 3) / 4;

  for (int l = 0; l < 3; ++l) {
    const u16* Wl = Wtg + (size_t)l * 3 * 16384;
    const float* bl = bb + (size_t)l * 3 * D;

    k_agg3<<<agg_blocks, 256, 0, stream>>>(h_all, csr_all, rs_all, cnt, M_all, N3);

    if (l < 2)
      k_gemm2<0><<<nbI + nbU, 256, 0, stream>>>(M_all, Wl, bl, cnt, h_all,
                                                (float*)d_out, NU, NI, nbI);
    else
      k_gemm2<1><<<nbI + nbU, 256, 0, stream>>>(M_all, Wl, bl, cnt, h_all,
                                                (float*)d_out, NU, NI, nbI);
  }
}